// Round 6
// baseline (4020.443 us; speedup 1.0000x reference)
//
#include <hip/hip_runtime.h>

#define GRIDW 512
#define RCH 16                          // channels per plane
#define TEXELS (GRIDW * GRIDW)          // 262144
#define PLANE_ELEMS (RCH * TEXELS)      // 4194304 floats per plane
#define NBIN_AX 4                       // bins per axis
#define NBINS 64                        // 4^3

typedef float f32x4 __attribute__((ext_vector_type(4)));

// ---------------------------------------------------------------------------
// Kernel 1: transpose each plane [16, 512, 512] -> [512, 512, 16]
// ---------------------------------------------------------------------------
__global__ __launch_bounds__(256) void transpose_planes_k(
    const float* __restrict__ p0, const float* __restrict__ p1,
    const float* __restrict__ p2, float* __restrict__ outT) {
  int bid = blockIdx.x;
  int plane = bid >> 10;                       // 1024 blocks of 256 per plane
  int t = ((bid & 1023) << 8) + threadIdx.x;   // texel index h*512+w
  const float* __restrict__ src = (plane == 0) ? p0 : (plane == 1) ? p1 : p2;
  float v[RCH];
#pragma unroll
  for (int r = 0; r < RCH; ++r)
    v[r] = __builtin_nontemporal_load(src + (size_t)r * TEXELS + t);
  f32x4* dst = reinterpret_cast<f32x4*>(outT + (size_t)plane * PLANE_ELEMS +
                                        (size_t)t * RCH);
#pragma unroll
  for (int c = 0; c < 4; ++c) {
    f32x4 q = {v[4 * c + 0], v[4 * c + 1], v[4 * c + 2], v[4 * c + 3]};
    dst[c] = q;
  }
}

// ---------------------------------------------------------------------------
// Shared helpers
// ---------------------------------------------------------------------------
__device__ __forceinline__ void norm3(const float* __restrict__ xyz,
                                      const float* __restrict__ mn,
                                      const float* __restrict__ mx, int i,
                                      float& nx, float& ny, float& nz) {
  float x = xyz[3 * i + 0];
  float y = xyz[3 * i + 1];
  float z = xyz[3 * i + 2];
  nx = (x - mn[0]) / (mx[0] - mn[0]) * 2.0f - 1.0f;
  ny = (y - mn[1]) / (mx[1] - mn[1]) * 2.0f - 1.0f;
  nz = (z - mn[2]) / (mx[2] - mn[2]) * 2.0f - 1.0f;
}

__device__ __forceinline__ int axbin(float u) {
  int b = (int)((u + 1.0f) * (0.5f * NBIN_AX));
  return min(max(b, 0), NBIN_AX - 1);
}

// bin id: bx major (XCD slabs), (by,bz) Morton-interleaved (2 bits each)
__device__ __forceinline__ int bin_from_n(float nx, float ny, float nz) {
  int bx = axbin(nx), by = axbin(ny), bz = axbin(nz);
  int m = ((by & 2) << 2) | ((bz & 2) << 1) | ((by & 1) << 1) | (bz & 1);
  return (bx << 4) | m;
}

__device__ __forceinline__ void axis_corners(float u, int& i0, int& i1,
                                             float& w0, float& w1) {
  float h = (u + 1.0f) * 0.5f * (float)(GRIDW - 1);
  float hf = floorf(h);
  float d = h - hf;
  int a = (int)hf;
  int b = a + 1;
  w0 = (a >= 0 && a < GRIDW) ? (1.0f - d) : 0.0f;
  w1 = (b >= 0 && b < GRIDW) ? d : 0.0f;
  i0 = min(max(a, 0), GRIDW - 1);
  i1 = min(max(b, 0), GRIDW - 1);
}

__device__ __forceinline__ void sample_plane_t(const f32x4* __restrict__ pT,
                                               float u, float v, f32x4 out[4]) {
  int h0, h1, w0, w1;
  float a0, a1, b0, b1;
  axis_corners(u, h0, h1, a0, a1);
  axis_corners(v, w0, w1, b0, b1);
  float W00 = a0 * b0, W01 = a0 * b1, W10 = a1 * b0, W11 = a1 * b1;
  const f32x4* p00 = pT + (size_t)(h0 * GRIDW + w0) * 4;
  const f32x4* p01 = pT + (size_t)(h0 * GRIDW + w1) * 4;
  const f32x4* p10 = pT + (size_t)(h1 * GRIDW + w0) * 4;
  const f32x4* p11 = pT + (size_t)(h1 * GRIDW + w1) * 4;
#pragma unroll
  for (int c = 0; c < 4; ++c) {
    out[c] = W00 * p00[c] + W01 * p01[c] + W10 * p10[c] + W11 * p11[c];
  }
}

// ---------------------------------------------------------------------------
// Kernel 2: per-bin histogram (LDS-aggregated)
// ---------------------------------------------------------------------------
__global__ __launch_bounds__(256) void hist_k(const float* __restrict__ xyz,
                                              const float* __restrict__ mn,
                                              const float* __restrict__ mx,
                                              int* __restrict__ counts, int n) {
  __shared__ int h[NBINS];
  for (int k = threadIdx.x; k < NBINS; k += 256) h[k] = 0;
  __syncthreads();
  int stride = gridDim.x * 256;
  for (int i = blockIdx.x * 256 + threadIdx.x; i < n; i += stride) {
    float nx, ny, nz;
    norm3(xyz, mn, mx, i, nx, ny, nz);
    atomicAdd(&h[bin_from_n(nx, ny, nz)], 1);
  }
  __syncthreads();
  for (int k = threadIdx.x; k < NBINS; k += 256) {
    int v = h[k];
    if (v) atomicAdd(&counts[k], v);
  }
}

// ---------------------------------------------------------------------------
// Kernel 3: exclusive scan over 64 bin counts (single wave)
// ---------------------------------------------------------------------------
__global__ __launch_bounds__(64) void scan_k(const int* __restrict__ counts,
                                             int* __restrict__ offsets) {
  __shared__ int s[NBINS];
  int t = threadIdx.x;
  int c = counts[t];
  s[t] = c;
  __syncthreads();
  for (int off = 1; off < NBINS; off <<= 1) {
    int v = (t >= off) ? s[t - off] : 0;
    __syncthreads();
    s[t] += v;
    __syncthreads();
  }
  offsets[t] = s[t] - c;  // exclusive
}

// ---------------------------------------------------------------------------
// Kernel 4: scatter {nx,ny,nz,orig_idx} records into bin-sorted order.
// cursors[] starts as exclusive offsets and is consumed (rebuilt every launch).
// ---------------------------------------------------------------------------
__global__ __launch_bounds__(256) void scatter_k(const float* __restrict__ xyz,
                                                 const float* __restrict__ mn,
                                                 const float* __restrict__ mx,
                                                 int* __restrict__ cursors,
                                                 f32x4* __restrict__ recs,
                                                 int n) {
  int i = blockIdx.x * 256 + threadIdx.x;
  if (i >= n) return;
  float nx, ny, nz;
  norm3(xyz, mn, mx, i, nx, ny, nz);
  int b = bin_from_n(nx, ny, nz);
  int pos = atomicAdd(&cursors[b], 1);
  f32x4 r = {nx, ny, nz, __uint_as_float((unsigned)i)};
  recs[pos] = r;
}

// ---------------------------------------------------------------------------
// Kernel 5: sample in bin-sorted order. XCD-swizzled blocks so each bin's
// blocks share one XCD's L2 (bin regions ~3 MB fit the 4 MB L2).
// ---------------------------------------------------------------------------
__global__ __launch_bounds__(256) void sample_sorted_k(
    const f32x4* __restrict__ recs, const float* __restrict__ planesT,
    float* __restrict__ out, int n, int nb) {
  int bid = blockIdx.x;
  if ((nb & 7) == 0) {                 // bijective XCD chunking (nb % 8 == 0)
    int c = nb >> 3;
    bid = (bid & 7) * c + (bid >> 3);
  }
  int i = bid * 256 + threadIdx.x;
  if (i >= n) return;
  f32x4 r = recs[i];
  float nx = r.x, ny = r.y, nz = r.z;
  unsigned orig = __float_as_uint(r.w);

  f32x4 res[12];
  const f32x4* pT = reinterpret_cast<const f32x4*>(planesT);
  sample_plane_t(pT + 0 * (PLANE_ELEMS / 4), nx, ny, &res[0]);  // xy
  sample_plane_t(pT + 1 * (PLANE_ELEMS / 4), nx, nz, &res[4]);  // xz
  sample_plane_t(pT + 2 * (PLANE_ELEMS / 4), ny, nz, &res[8]);  // yz

  f32x4* o = reinterpret_cast<f32x4*>(out + (size_t)orig * 48);
#pragma unroll
  for (int k = 0; k < 12; ++k) o[k] = res[k];
}

// ---------------------------------------------------------------------------
// Legacy unsorted sampler (fallback when ws can't hold rec array)
// ---------------------------------------------------------------------------
__global__ __launch_bounds__(256) void sample_k(
    const float* __restrict__ xyz, const float* __restrict__ planesT,
    const float* __restrict__ mn, const float* __restrict__ mx,
    float* __restrict__ out, int n) {
  int i = blockIdx.x * 256 + threadIdx.x;
  if (i >= n) return;
  float nx, ny, nz;
  norm3(xyz, mn, mx, i, nx, ny, nz);
  f32x4 res[12];
  const f32x4* pT = reinterpret_cast<const f32x4*>(planesT);
  sample_plane_t(pT + 0 * (PLANE_ELEMS / 4), nx, ny, &res[0]);
  sample_plane_t(pT + 1 * (PLANE_ELEMS / 4), nx, nz, &res[4]);
  sample_plane_t(pT + 2 * (PLANE_ELEMS / 4), ny, nz, &res[8]);
  f32x4* o = reinterpret_cast<f32x4*>(out + (size_t)i * 48);
#pragma unroll
  for (int k = 0; k < 12; ++k) o[k] = res[k];
}

// ---------------------------------------------------------------------------
// Direct fallback (ws too small for anything)
// ---------------------------------------------------------------------------
__global__ __launch_bounds__(256) void sample_direct_k(
    const float* __restrict__ xyz, const float* __restrict__ p0,
    const float* __restrict__ p1, const float* __restrict__ p2,
    const float* __restrict__ mn, const float* __restrict__ mx,
    float* __restrict__ out, int n) {
  int i = blockIdx.x * 256 + threadIdx.x;
  if (i >= n) return;
  float c3[3];
  norm3(xyz, mn, mx, i, c3[0], c3[1], c3[2]);
  const float* planes[3] = {p0, p1, p2};
  const int ui[3] = {0, 0, 1};
  const int vi[3] = {1, 2, 2};
  for (int p = 0; p < 3; ++p) {
    int h0, h1, w0, w1;
    float a0, a1, b0, b1;
    axis_corners(c3[ui[p]], h0, h1, a0, a1);
    axis_corners(c3[vi[p]], w0, w1, b0, b1);
    float W00 = a0 * b0, W01 = a0 * b1, W10 = a1 * b0, W11 = a1 * b1;
    const float* pl = planes[p];
    int t00 = h0 * GRIDW + w0, t01 = h0 * GRIDW + w1;
    int t10 = h1 * GRIDW + w0, t11 = h1 * GRIDW + w1;
#pragma unroll
    for (int r = 0; r < RCH; ++r) {
      const float* base = pl + (size_t)r * TEXELS;
      out[(size_t)i * 48 + p * RCH + r] = W00 * base[t00] + W01 * base[t01] +
                                          W10 * base[t10] + W11 * base[t11];
    }
  }
}

extern "C" void kernel_launch(void* const* d_in, const int* in_sizes, int n_in,
                              void* d_out, int out_size, void* d_ws,
                              size_t ws_size, hipStream_t stream) {
  const float* xyz = (const float*)d_in[0];
  const float* xy_plane = (const float*)d_in[1];
  const float* xz_plane = (const float*)d_in[2];
  const float* yz_plane = (const float*)d_in[3];
  const float* mn = (const float*)d_in[4];
  const float* mx = (const float*)d_in[5];
  float* out = (float*)d_out;
  int n = in_sizes[0] / 3;
  int nb = (n + 255) / 256;

  size_t planesT_bytes = (size_t)3 * PLANE_ELEMS * sizeof(float);  // 50.3 MB
  size_t rec_off = planesT_bytes;
  size_t rec_bytes = (size_t)n * 16;
  size_t cnt_off = rec_off + rec_bytes;
  size_t need_binned = cnt_off + 2 * NBINS * sizeof(int);

  if (ws_size >= need_binned) {
    float* planesT = (float*)d_ws;
    f32x4* recs = (f32x4*)((char*)d_ws + rec_off);
    int* counts = (int*)((char*)d_ws + cnt_off);
    int* offsets = counts + NBINS;

    hipMemsetAsync(counts, 0, NBINS * sizeof(int), stream);
    transpose_planes_k<<<3 * (TEXELS / 256), 256, 0, stream>>>(
        xy_plane, xz_plane, yz_plane, planesT);
    hist_k<<<512, 256, 0, stream>>>(xyz, mn, mx, counts, n);
    scan_k<<<1, 64, 0, stream>>>(counts, offsets);
    scatter_k<<<nb, 256, 0, stream>>>(xyz, mn, mx, offsets, recs, n);
    sample_sorted_k<<<nb, 256, 0, stream>>>(recs, (const float*)planesT, out, n,
                                            nb);
  } else if (ws_size >= planesT_bytes) {
    float* planesT = (float*)d_ws;
    transpose_planes_k<<<3 * (TEXELS / 256), 256, 0, stream>>>(
        xy_plane, xz_plane, yz_plane, planesT);
    sample_k<<<nb, 256, 0, stream>>>(xyz, planesT, mn, mx, out, n);
  } else {
    sample_direct_k<<<nb, 256, 0, stream>>>(xyz, xy_plane, xz_plane, yz_plane,
                                            mn, mx, out, n);
  }
}

// Round 8
// 967.156 us; speedup vs baseline: 4.1570x; 4.1570x over previous
//
#include <hip/hip_runtime.h>

#define GRIDW 512
#define RCH 16                          // channels per plane
#define TEXELS (GRIDW * GRIDW)          // 262144
#define PLANE_ELEMS (RCH * TEXELS)      // 4194304 floats per plane
#define NBIN_AX 4                       // bins per axis
#define NBINS 64                        // 4^3
#define CSTRIDE 32                      // counter padding: 32 ints = 128 B/line

typedef float f32x4 __attribute__((ext_vector_type(4)));

// ---------------------------------------------------------------------------
// Kernel 1: transpose each plane [16, 512, 512] -> [512, 512, 16]
// ---------------------------------------------------------------------------
__global__ __launch_bounds__(256) void transpose_planes_k(
    const float* __restrict__ p0, const float* __restrict__ p1,
    const float* __restrict__ p2, float* __restrict__ outT) {
  int bid = blockIdx.x;
  int plane = bid >> 10;                       // 1024 blocks of 256 per plane
  int t = ((bid & 1023) << 8) + threadIdx.x;   // texel index h*512+w
  const float* __restrict__ src = (plane == 0) ? p0 : (plane == 1) ? p1 : p2;
  float v[RCH];
#pragma unroll
  for (int r = 0; r < RCH; ++r)
    v[r] = __builtin_nontemporal_load(src + (size_t)r * TEXELS + t);
  f32x4* dst = reinterpret_cast<f32x4*>(outT + (size_t)plane * PLANE_ELEMS +
                                        (size_t)t * RCH);
#pragma unroll
  for (int c = 0; c < 4; ++c) {
    f32x4 q = {v[4 * c + 0], v[4 * c + 1], v[4 * c + 2], v[4 * c + 3]};
    dst[c] = q;
  }
}

// ---------------------------------------------------------------------------
// Shared helpers
// ---------------------------------------------------------------------------
__device__ __forceinline__ void norm3(const float* __restrict__ xyz,
                                      const float* __restrict__ mn,
                                      const float* __restrict__ mx, int i,
                                      float& nx, float& ny, float& nz) {
  float x = xyz[3 * i + 0];
  float y = xyz[3 * i + 1];
  float z = xyz[3 * i + 2];
  nx = (x - mn[0]) / (mx[0] - mn[0]) * 2.0f - 1.0f;
  ny = (y - mn[1]) / (mx[1] - mn[1]) * 2.0f - 1.0f;
  nz = (z - mn[2]) / (mx[2] - mn[2]) * 2.0f - 1.0f;
}

__device__ __forceinline__ int axbin(float u) {
  int b = (int)((u + 1.0f) * (0.5f * NBIN_AX));
  return min(max(b, 0), NBIN_AX - 1);
}

// bin id: bx major (XCD slabs), (by,bz) Morton-interleaved (2 bits each)
__device__ __forceinline__ int bin_from_n(float nx, float ny, float nz) {
  int bx = axbin(nx), by = axbin(ny), bz = axbin(nz);
  int m = ((by & 2) << 2) | ((bz & 2) << 1) | ((by & 1) << 1) | (bz & 1);
  return (bx << 4) | m;
}

__device__ __forceinline__ void axis_corners(float u, int& i0, int& i1,
                                             float& w0, float& w1) {
  float h = (u + 1.0f) * 0.5f * (float)(GRIDW - 1);
  float hf = floorf(h);
  float d = h - hf;
  int a = (int)hf;
  int b = a + 1;
  w0 = (a >= 0 && a < GRIDW) ? (1.0f - d) : 0.0f;
  w1 = (b >= 0 && b < GRIDW) ? d : 0.0f;
  i0 = min(max(a, 0), GRIDW - 1);
  i1 = min(max(b, 0), GRIDW - 1);
}

__device__ __forceinline__ void sample_plane_t(const f32x4* __restrict__ pT,
                                               float u, float v, f32x4 out[4]) {
  int h0, h1, w0, w1;
  float a0, a1, b0, b1;
  axis_corners(u, h0, h1, a0, a1);
  axis_corners(v, w0, w1, b0, b1);
  float W00 = a0 * b0, W01 = a0 * b1, W10 = a1 * b0, W11 = a1 * b1;
  const f32x4* p00 = pT + (size_t)(h0 * GRIDW + w0) * 4;
  const f32x4* p01 = pT + (size_t)(h0 * GRIDW + w1) * 4;
  const f32x4* p10 = pT + (size_t)(h1 * GRIDW + w0) * 4;
  const f32x4* p11 = pT + (size_t)(h1 * GRIDW + w1) * 4;
#pragma unroll
  for (int c = 0; c < 4; ++c) {
    out[c] = W00 * p00[c] + W01 * p01[c] + W10 * p10[c] + W11 * p11[c];
  }
}

// ---------------------------------------------------------------------------
// Kernel 2: per-bin histogram (LDS-aggregated; padded global counters)
// ---------------------------------------------------------------------------
__global__ __launch_bounds__(256) void hist_k(const float* __restrict__ xyz,
                                              const float* __restrict__ mn,
                                              const float* __restrict__ mx,
                                              int* __restrict__ counts, int n) {
  __shared__ int h[NBINS];
  for (int k = threadIdx.x; k < NBINS; k += 256) h[k] = 0;
  __syncthreads();
  int stride = gridDim.x * 256;
  for (int i = blockIdx.x * 256 + threadIdx.x; i < n; i += stride) {
    float nx, ny, nz;
    norm3(xyz, mn, mx, i, nx, ny, nz);
    atomicAdd(&h[bin_from_n(nx, ny, nz)], 1);
  }
  __syncthreads();
  for (int k = threadIdx.x; k < NBINS; k += 256) {
    int v = h[k];
    if (v) atomicAdd(&counts[k * CSTRIDE], v);
  }
}

// ---------------------------------------------------------------------------
// Kernel 3: exclusive scan over 64 padded bin counts (single wave)
// ---------------------------------------------------------------------------
__global__ __launch_bounds__(64) void scan_k(const int* __restrict__ counts,
                                             int* __restrict__ offsets) {
  __shared__ int s[NBINS];
  int t = threadIdx.x;
  int c = counts[t * CSTRIDE];
  s[t] = c;
  __syncthreads();
  for (int off = 1; off < NBINS; off <<= 1) {
    int v = (t >= off) ? s[t - off] : 0;
    __syncthreads();
    s[t] += v;
    __syncthreads();
  }
  offsets[t * CSTRIDE] = s[t] - c;  // exclusive
}

// ---------------------------------------------------------------------------
// Kernel 4: scatter records into bin order. Block-aggregated: LDS local
// ranks + one padded global atomicAdd per (block,bin) chunk reservation.
// Chunk reservation => per-(block,bin) records are contiguous => writes merge.
// ---------------------------------------------------------------------------
__global__ __launch_bounds__(256) void scatter_k(const float* __restrict__ xyz,
                                                 const float* __restrict__ mn,
                                                 const float* __restrict__ mx,
                                                 int* __restrict__ cursors,
                                                 f32x4* __restrict__ recs,
                                                 int n) {
  __shared__ int lh[NBINS];
  __shared__ int lbase[NBINS];
  for (int k = threadIdx.x; k < NBINS; k += 256) lh[k] = 0;
  __syncthreads();
  int i = blockIdx.x * 256 + threadIdx.x;
  bool valid = i < n;
  float nx = 0.f, ny = 0.f, nz = 0.f;
  int b = 0, lr = 0;
  if (valid) {
    norm3(xyz, mn, mx, i, nx, ny, nz);
    b = bin_from_n(nx, ny, nz);
    lr = atomicAdd(&lh[b], 1);  // local rank within (block, bin)
  }
  __syncthreads();
  for (int k = threadIdx.x; k < NBINS; k += 256) {
    int c = lh[k];
    lbase[k] = c ? atomicAdd(&cursors[k * CSTRIDE], c) : 0;
  }
  __syncthreads();
  if (valid) {
    f32x4 r = {nx, ny, nz, __uint_as_float((unsigned)i)};
    recs[(size_t)lbase[b] + lr] = r;
  }
}

// ---------------------------------------------------------------------------
// Kernel 5: sample in bin-sorted order. XCD-swizzled blocks so each bin's
// blocks share one XCD's L2 (bin regions ~3 MB fit the 4 MB L2).
// ---------------------------------------------------------------------------
__global__ __launch_bounds__(256) void sample_sorted_k(
    const f32x4* __restrict__ recs, const float* __restrict__ planesT,
    float* __restrict__ out, int n, int nb) {
  int bid = blockIdx.x;
  if ((nb & 7) == 0) {                 // bijective XCD chunking (nb % 8 == 0)
    int c = nb >> 3;
    bid = (bid & 7) * c + (bid >> 3);
  }
  int i = bid * 256 + threadIdx.x;
  if (i >= n) return;
  f32x4 r = recs[i];
  float nx = r.x, ny = r.y, nz = r.z;
  unsigned orig = __float_as_uint(r.w);

  f32x4 res[12];
  const f32x4* pT = reinterpret_cast<const f32x4*>(planesT);
  sample_plane_t(pT + 0 * (PLANE_ELEMS / 4), nx, ny, &res[0]);  // xy
  sample_plane_t(pT + 1 * (PLANE_ELEMS / 4), nx, nz, &res[4]);  // xz
  sample_plane_t(pT + 2 * (PLANE_ELEMS / 4), ny, nz, &res[8]);  // yz

  f32x4* o = reinterpret_cast<f32x4*>(out + (size_t)orig * 48);
#pragma unroll
  for (int k = 0; k < 12; ++k) o[k] = res[k];
}

// ---------------------------------------------------------------------------
// Legacy unsorted sampler (fallback when ws can't hold rec array)
// ---------------------------------------------------------------------------
__global__ __launch_bounds__(256) void sample_k(
    const float* __restrict__ xyz, const float* __restrict__ planesT,
    const float* __restrict__ mn, const float* __restrict__ mx,
    float* __restrict__ out, int n) {
  int i = blockIdx.x * 256 + threadIdx.x;
  if (i >= n) return;
  float nx, ny, nz;
  norm3(xyz, mn, mx, i, nx, ny, nz);
  f32x4 res[12];
  const f32x4* pT = reinterpret_cast<const f32x4*>(planesT);
  sample_plane_t(pT + 0 * (PLANE_ELEMS / 4), nx, ny, &res[0]);
  sample_plane_t(pT + 1 * (PLANE_ELEMS / 4), nx, nz, &res[4]);
  sample_plane_t(pT + 2 * (PLANE_ELEMS / 4), ny, nz, &res[8]);
  f32x4* o = reinterpret_cast<f32x4*>(out + (size_t)i * 48);
#pragma unroll
  for (int k = 0; k < 12; ++k) o[k] = res[k];
}

// ---------------------------------------------------------------------------
// Direct fallback (ws too small for anything)
// ---------------------------------------------------------------------------
__global__ __launch_bounds__(256) void sample_direct_k(
    const float* __restrict__ xyz, const float* __restrict__ p0,
    const float* __restrict__ p1, const float* __restrict__ p2,
    const float* __restrict__ mn, const float* __restrict__ mx,
    float* __restrict__ out, int n) {
  int i = blockIdx.x * 256 + threadIdx.x;
  if (i >= n) return;
  float c3[3];
  norm3(xyz, mn, mx, i, c3[0], c3[1], c3[2]);
  const float* planes[3] = {p0, p1, p2};
  const int ui[3] = {0, 0, 1};
  const int vi[3] = {1, 2, 2};
  for (int p = 0; p < 3; ++p) {
    int h0, h1, w0, w1;
    float a0, a1, b0, b1;
    axis_corners(c3[ui[p]], h0, h1, a0, a1);
    axis_corners(c3[vi[p]], w0, w1, b0, b1);
    float W00 = a0 * b0, W01 = a0 * b1, W10 = a1 * b0, W11 = a1 * b1;
    const float* pl = planes[p];
    int t00 = h0 * GRIDW + w0, t01 = h0 * GRIDW + w1;
    int t10 = h1 * GRIDW + w0, t11 = h1 * GRIDW + w1;
#pragma unroll
    for (int r = 0; r < RCH; ++r) {
      const float* base = pl + (size_t)r * TEXELS;
      out[(size_t)i * 48 + p * RCH + r] = W00 * base[t00] + W01 * base[t01] +
                                          W10 * base[t10] + W11 * base[t11];
    }
  }
}

extern "C" void kernel_launch(void* const* d_in, const int* in_sizes, int n_in,
                              void* d_out, int out_size, void* d_ws,
                              size_t ws_size, hipStream_t stream) {
  const float* xyz = (const float*)d_in[0];
  const float* xy_plane = (const float*)d_in[1];
  const float* xz_plane = (const float*)d_in[2];
  const float* yz_plane = (const float*)d_in[3];
  const float* mn = (const float*)d_in[4];
  const float* mx = (const float*)d_in[5];
  float* out = (float*)d_out;
  int n = in_sizes[0] / 3;
  int nb = (n + 255) / 256;

  size_t planesT_bytes = (size_t)3 * PLANE_ELEMS * sizeof(float);  // 50.3 MB
  size_t rec_off = planesT_bytes;
  size_t rec_bytes = (size_t)n * 16;
  size_t cnt_off = rec_off + rec_bytes;
  size_t cnt_bytes = (size_t)NBINS * CSTRIDE * sizeof(int);
  size_t need_binned = cnt_off + 2 * cnt_bytes;

  if (ws_size >= need_binned) {
    float* planesT = (float*)d_ws;
    f32x4* recs = (f32x4*)((char*)d_ws + rec_off);
    int* counts = (int*)((char*)d_ws + cnt_off);
    int* offsets = (int*)((char*)d_ws + cnt_off + cnt_bytes);

    hipMemsetAsync(counts, 0, cnt_bytes, stream);
    transpose_planes_k<<<3 * (TEXELS / 256), 256, 0, stream>>>(
        xy_plane, xz_plane, yz_plane, planesT);
    hist_k<<<512, 256, 0, stream>>>(xyz, mn, mx, counts, n);
    scan_k<<<1, 64, 0, stream>>>(counts, offsets);
    scatter_k<<<nb, 256, 0, stream>>>(xyz, mn, mx, offsets, recs, n);
    sample_sorted_k<<<nb, 256, 0, stream>>>(recs, (const float*)planesT, out, n,
                                            nb);
  } else if (ws_size >= planesT_bytes) {
    float* planesT = (float*)d_ws;
    transpose_planes_k<<<3 * (TEXELS / 256), 256, 0, stream>>>(
        xy_plane, xz_plane, yz_plane, planesT);
    sample_k<<<nb, 256, 0, stream>>>(xyz, planesT, mn, mx, out, n);
  } else {
    sample_direct_k<<<nb, 256, 0, stream>>>(xyz, xy_plane, xz_plane, yz_plane,
                                            mn, mx, out, n);
  }
}

// Round 10
// 664.078 us; speedup vs baseline: 6.0542x; 1.4564x over previous
//
#include <hip/hip_runtime.h>

#define GRIDW 512
#define RCH 16                          // channels per plane
#define TEXELS (GRIDW * GRIDW)          // 262144
#define PLANE_ELEMS (RCH * TEXELS)      // 4194304 floats per plane
#define NBIN_AX 4                       // bins per axis
#define NBINS 64                        // 4^3
#define NGROUPS 1024                    // scatter groups (blocks)

typedef float f32x4 __attribute__((ext_vector_type(4)));

// ---------------------------------------------------------------------------
// Kernel 1: transpose each plane [16, 512, 512] -> [512, 512, 16]
// ---------------------------------------------------------------------------
__global__ __launch_bounds__(256) void transpose_planes_k(
    const float* __restrict__ p0, const float* __restrict__ p1,
    const float* __restrict__ p2, float* __restrict__ outT) {
  int bid = blockIdx.x;
  int plane = bid >> 10;                       // 1024 blocks of 256 per plane
  int t = ((bid & 1023) << 8) + threadIdx.x;   // texel index h*512+w
  const float* __restrict__ src = (plane == 0) ? p0 : (plane == 1) ? p1 : p2;
  float v[RCH];
#pragma unroll
  for (int r = 0; r < RCH; ++r)
    v[r] = __builtin_nontemporal_load(src + (size_t)r * TEXELS + t);
  f32x4* dst = reinterpret_cast<f32x4*>(outT + (size_t)plane * PLANE_ELEMS +
                                        (size_t)t * RCH);
#pragma unroll
  for (int c = 0; c < 4; ++c) {
    f32x4 q = {v[4 * c + 0], v[4 * c + 1], v[4 * c + 2], v[4 * c + 3]};
    dst[c] = q;
  }
}

// ---------------------------------------------------------------------------
// Shared helpers
// ---------------------------------------------------------------------------
__device__ __forceinline__ void norm3(const float* __restrict__ xyz,
                                      const float* __restrict__ mn,
                                      const float* __restrict__ mx, int i,
                                      float& nx, float& ny, float& nz) {
  float x = xyz[3 * i + 0];
  float y = xyz[3 * i + 1];
  float z = xyz[3 * i + 2];
  nx = (x - mn[0]) / (mx[0] - mn[0]) * 2.0f - 1.0f;
  ny = (y - mn[1]) / (mx[1] - mn[1]) * 2.0f - 1.0f;
  nz = (z - mn[2]) / (mx[2] - mn[2]) * 2.0f - 1.0f;
}

__device__ __forceinline__ int axbin(float u) {
  int b = (int)((u + 1.0f) * (0.5f * NBIN_AX));
  return min(max(b, 0), NBIN_AX - 1);
}

// bin id: bx major (XCD slabs), (by,bz) Morton-interleaved (2 bits each)
__device__ __forceinline__ int bin_from_n(float nx, float ny, float nz) {
  int bx = axbin(nx), by = axbin(ny), bz = axbin(nz);
  int m = ((by & 2) << 2) | ((bz & 2) << 1) | ((by & 1) << 1) | (bz & 1);
  return (bx << 4) | m;
}

__device__ __forceinline__ void axis_corners(float u, int& i0, int& i1,
                                             float& w0, float& w1) {
  float h = (u + 1.0f) * 0.5f * (float)(GRIDW - 1);
  float hf = floorf(h);
  float d = h - hf;
  int a = (int)hf;
  int b = a + 1;
  w0 = (a >= 0 && a < GRIDW) ? (1.0f - d) : 0.0f;
  w1 = (b >= 0 && b < GRIDW) ? d : 0.0f;
  i0 = min(max(a, 0), GRIDW - 1);
  i1 = min(max(b, 0), GRIDW - 1);
}

__device__ __forceinline__ void sample_plane_t(const f32x4* __restrict__ pT,
                                               float u, float v, f32x4 out[4]) {
  int h0, h1, w0, w1;
  float a0, a1, b0, b1;
  axis_corners(u, h0, h1, a0, a1);
  axis_corners(v, w0, w1, b0, b1);
  float W00 = a0 * b0, W01 = a0 * b1, W10 = a1 * b0, W11 = a1 * b1;
  const f32x4* p00 = pT + (size_t)(h0 * GRIDW + w0) * 4;
  const f32x4* p01 = pT + (size_t)(h0 * GRIDW + w1) * 4;
  const f32x4* p10 = pT + (size_t)(h1 * GRIDW + w0) * 4;
  const f32x4* p11 = pT + (size_t)(h1 * GRIDW + w1) * 4;
#pragma unroll
  for (int c = 0; c < 4; ++c) {
    out[c] = W00 * p00[c] + W01 * p01[c] + W10 * p10[c] + W11 * p11[c];
  }
}

// ---------------------------------------------------------------------------
// Kernel 2: per-group histogram. Group g owns points [g*ppb, (g+1)*ppb).
// Hp[g*64+b] = count. No global atomics.
// ---------------------------------------------------------------------------
__global__ __launch_bounds__(256) void hist2_k(const float* __restrict__ xyz,
                                               const float* __restrict__ mn,
                                               const float* __restrict__ mx,
                                               int* __restrict__ Hp, int n,
                                               int ppb) {
  __shared__ int h[NBINS];
  for (int k = threadIdx.x; k < NBINS; k += 256) h[k] = 0;
  __syncthreads();
  int g = blockIdx.x;
  int end = min(n, (g + 1) * ppb);
  for (int i = g * ppb + threadIdx.x; i < end; i += 256) {
    float nx, ny, nz;
    norm3(xyz, mn, mx, i, nx, ny, nz);
    atomicAdd(&h[bin_from_n(nx, ny, nz)], 1);
  }
  __syncthreads();
  for (int k = threadIdx.x; k < NBINS; k += 256) Hp[g * NBINS + k] = h[k];
}

// ---------------------------------------------------------------------------
// Kernel 3a: per-bin exclusive scan over the NGROUPS group-counts.
// Block b scans column b of Hp: Pg[g*64+b] = sum_{g'<g} Hp[g'*64+b]; T[b]=total.
// ---------------------------------------------------------------------------
__global__ __launch_bounds__(256) void colscan_k(const int* __restrict__ Hp,
                                                 int* __restrict__ Pg,
                                                 int* __restrict__ T) {
  int b = blockIdx.x;  // bin
  int t = threadIdx.x;
  __shared__ int s[256];
  int v[NGROUPS / 256];
  int sum = 0;
#pragma unroll
  for (int e = 0; e < NGROUPS / 256; ++e) {
    v[e] = Hp[(t * (NGROUPS / 256) + e) * NBINS + b];
    sum += v[e];
  }
  s[t] = sum;
  __syncthreads();
  for (int off = 1; off < 256; off <<= 1) {
    int x = (t >= off) ? s[t - off] : 0;
    __syncthreads();
    s[t] += x;
    __syncthreads();
  }
  int run = s[t] - sum;  // exclusive across threads
#pragma unroll
  for (int e = 0; e < NGROUPS / 256; ++e) {
    Pg[(t * (NGROUPS / 256) + e) * NBINS + b] = run;
    run += v[e];
  }
  if (t == 255) T[b] = run;
}

// ---------------------------------------------------------------------------
// Kernel 3b: exclusive scan of 64 bin totals -> bin bases B.
// ---------------------------------------------------------------------------
__global__ __launch_bounds__(64) void binbase_k(const int* __restrict__ T,
                                                int* __restrict__ B) {
  __shared__ int s[NBINS];
  int t = threadIdx.x;
  int c = T[t];
  s[t] = c;
  __syncthreads();
  for (int off = 1; off < NBINS; off <<= 1) {
    int v = (t >= off) ? s[t - off] : 0;
    __syncthreads();
    s[t] += v;
    __syncthreads();
  }
  B[t] = s[t] - c;
}

// ---------------------------------------------------------------------------
// Kernel 4: atomic-free scatter. pos = B[bin] + Pg[g][bin] + LDS-rank.
// Only LDS atomics; positions deterministic per (g,bin) segment.
// ---------------------------------------------------------------------------
__global__ __launch_bounds__(256) void scatter2_k(
    const float* __restrict__ xyz, const float* __restrict__ mn,
    const float* __restrict__ mx, const int* __restrict__ Pg,
    const int* __restrict__ B, f32x4* __restrict__ recs, int n, int ppb) {
  __shared__ int run[NBINS];
  __shared__ int gbase[NBINS];
  int g = blockIdx.x;
  for (int k = threadIdx.x; k < NBINS; k += 256) {
    run[k] = 0;
    gbase[k] = B[k] + Pg[g * NBINS + k];
  }
  __syncthreads();
  int end = min(n, (g + 1) * ppb);
  for (int i = g * ppb + threadIdx.x; i < end; i += 256) {
    float nx, ny, nz;
    norm3(xyz, mn, mx, i, nx, ny, nz);
    int b = bin_from_n(nx, ny, nz);
    int lr = atomicAdd(&run[b], 1);
    f32x4 r = {nx, ny, nz, __uint_as_float((unsigned)i)};
    recs[(size_t)gbase[b] + lr] = r;
  }
}

// ---------------------------------------------------------------------------
// Kernel 5: 4-lanes-per-point sampler. Lanes j=0..3 of a point load the 4
// contiguous 16 B chunks of each 64 B texel -> HW coalesces to ONE line
// request per (point, corner): 16 line-reqs per wave-instr instead of 64.
// Lane j owns channel chunk j end-to-end (no cross-lane).
// ---------------------------------------------------------------------------
__global__ __launch_bounds__(256) void sample_sorted4_k(
    const f32x4* __restrict__ recs, const float* __restrict__ planesT,
    float* __restrict__ out, int n, int nb) {
  int bid = blockIdx.x;
  if ((nb & 7) == 0) {                 // bijective XCD chunking (nb % 8 == 0)
    int c = nb >> 3;
    bid = (bid & 7) * c + (bid >> 3);
  }
  int p = threadIdx.x >> 2;            // point within block (64 per block)
  int j = threadIdx.x & 3;             // channel chunk 0..3
  int i = bid * 64 + p;
  if (i >= n) return;
  f32x4 r = recs[i];                   // 4 lanes broadcast-read same 16 B
  float nx = r.x, ny = r.y, nz = r.z;
  unsigned orig = __float_as_uint(r.w);

  const float uu[3] = {nx, nx, ny};
  const float vv[3] = {ny, nz, nz};
  float* o = out + (size_t)orig * 48 + j * 4;
#pragma unroll
  for (int pl = 0; pl < 3; ++pl) {
    int h0, h1, w0, w1;
    float a0, a1, b0, b1;
    axis_corners(uu[pl], h0, h1, a0, a1);
    axis_corners(vv[pl], w0, w1, b0, b1);
    float W00 = a0 * b0, W01 = a0 * b1, W10 = a1 * b0, W11 = a1 * b1;
    const f32x4* pT =
        reinterpret_cast<const f32x4*>(planesT) + (size_t)pl * (PLANE_ELEMS / 4);
    f32x4 acc = W00 * pT[(size_t)(h0 * GRIDW + w0) * 4 + j] +
                W01 * pT[(size_t)(h0 * GRIDW + w1) * 4 + j] +
                W10 * pT[(size_t)(h1 * GRIDW + w0) * 4 + j] +
                W11 * pT[(size_t)(h1 * GRIDW + w1) * 4 + j];
    *reinterpret_cast<f32x4*>(o + pl * 16) = acc;
  }
}

// ---------------------------------------------------------------------------
// Legacy unsorted sampler (fallback when ws can't hold sort arrays)
// ---------------------------------------------------------------------------
__global__ __launch_bounds__(256) void sample_k(
    const float* __restrict__ xyz, const float* __restrict__ planesT,
    const float* __restrict__ mn, const float* __restrict__ mx,
    float* __restrict__ out, int n) {
  int i = blockIdx.x * 256 + threadIdx.x;
  if (i >= n) return;
  float nx, ny, nz;
  norm3(xyz, mn, mx, i, nx, ny, nz);
  f32x4 res[12];
  const f32x4* pT = reinterpret_cast<const f32x4*>(planesT);
  sample_plane_t(pT + 0 * (PLANE_ELEMS / 4), nx, ny, &res[0]);
  sample_plane_t(pT + 1 * (PLANE_ELEMS / 4), nx, nz, &res[4]);
  sample_plane_t(pT + 2 * (PLANE_ELEMS / 4), ny, nz, &res[8]);
  f32x4* o = reinterpret_cast<f32x4*>(out + (size_t)i * 48);
#pragma unroll
  for (int k = 0; k < 12; ++k) o[k] = res[k];
}

// ---------------------------------------------------------------------------
// Direct fallback (ws too small for anything)
// ---------------------------------------------------------------------------
__global__ __launch_bounds__(256) void sample_direct_k(
    const float* __restrict__ xyz, const float* __restrict__ p0,
    const float* __restrict__ p1, const float* __restrict__ p2,
    const float* __restrict__ mn, const float* __restrict__ mx,
    float* __restrict__ out, int n) {
  int i = blockIdx.x * 256 + threadIdx.x;
  if (i >= n) return;
  float c3[3];
  norm3(xyz, mn, mx, i, c3[0], c3[1], c3[2]);
  const float* planes[3] = {p0, p1, p2};
  const int ui[3] = {0, 0, 1};
  const int vi[3] = {1, 2, 2};
  for (int p = 0; p < 3; ++p) {
    int h0, h1, w0, w1;
    float a0, a1, b0, b1;
    axis_corners(c3[ui[p]], h0, h1, a0, a1);
    axis_corners(c3[vi[p]], w0, w1, b0, b1);
    float W00 = a0 * b0, W01 = a0 * b1, W10 = a1 * b0, W11 = a1 * b1;
    const float* pl = planes[p];
    int t00 = h0 * GRIDW + w0, t01 = h0 * GRIDW + w1;
    int t10 = h1 * GRIDW + w0, t11 = h1 * GRIDW + w1;
#pragma unroll
    for (int r = 0; r < RCH; ++r) {
      const float* base = pl + (size_t)r * TEXELS;
      out[(size_t)i * 48 + p * RCH + r] = W00 * base[t00] + W01 * base[t01] +
                                          W10 * base[t10] + W11 * base[t11];
    }
  }
}

extern "C" void kernel_launch(void* const* d_in, const int* in_sizes, int n_in,
                              void* d_out, int out_size, void* d_ws,
                              size_t ws_size, hipStream_t stream) {
  const float* xyz = (const float*)d_in[0];
  const float* xy_plane = (const float*)d_in[1];
  const float* xz_plane = (const float*)d_in[2];
  const float* yz_plane = (const float*)d_in[3];
  const float* mn = (const float*)d_in[4];
  const float* mx = (const float*)d_in[5];
  float* out = (float*)d_out;
  int n = in_sizes[0] / 3;
  int nb = (n + 255) / 256;
  int ppb = (n + NGROUPS - 1) / NGROUPS;

  size_t planesT_bytes = (size_t)3 * PLANE_ELEMS * sizeof(float);  // 50.3 MB
  size_t rec_off = planesT_bytes;
  size_t rec_bytes = (size_t)n * 16;
  size_t hp_off = rec_off + rec_bytes;
  size_t grp_bytes = (size_t)NGROUPS * NBINS * sizeof(int);  // 256 KB
  size_t pg_off = hp_off + grp_bytes;
  size_t t_off = pg_off + grp_bytes;
  size_t b_off = t_off + NBINS * sizeof(int);
  size_t need_binned = b_off + NBINS * sizeof(int);

  if (ws_size >= need_binned) {
    float* planesT = (float*)d_ws;
    f32x4* recs = (f32x4*)((char*)d_ws + rec_off);
    int* Hp = (int*)((char*)d_ws + hp_off);
    int* Pg = (int*)((char*)d_ws + pg_off);
    int* T = (int*)((char*)d_ws + t_off);
    int* B = (int*)((char*)d_ws + b_off);

    transpose_planes_k<<<3 * (TEXELS / 256), 256, 0, stream>>>(
        xy_plane, xz_plane, yz_plane, planesT);
    hist2_k<<<NGROUPS, 256, 0, stream>>>(xyz, mn, mx, Hp, n, ppb);
    colscan_k<<<NBINS, 256, 0, stream>>>(Hp, Pg, T);
    binbase_k<<<1, 64, 0, stream>>>(T, B);
    scatter2_k<<<NGROUPS, 256, 0, stream>>>(xyz, mn, mx, Pg, B, recs, n, ppb);
    int nb4 = (n + 63) / 64;
    sample_sorted4_k<<<nb4, 256, 0, stream>>>(recs, (const float*)planesT, out,
                                              n, nb4);
  } else if (ws_size >= planesT_bytes) {
    float* planesT = (float*)d_ws;
    transpose_planes_k<<<3 * (TEXELS / 256), 256, 0, stream>>>(
        xy_plane, xz_plane, yz_plane, planesT);
    sample_k<<<nb, 256, 0, stream>>>(xyz, planesT, mn, mx, out, n);
  } else {
    sample_direct_k<<<nb, 256, 0, stream>>>(xyz, xy_plane, xz_plane, yz_plane,
                                            mn, mx, out, n);
  }
}